// Round 6
// baseline (80.169 us; speedup 1.0000x reference)
//
#include <hip/hip_runtime.h>
#include <hip/hip_bf16.h>

// DirectionalConv mode='down': out[b,co,d,h,w] =
//   sum_{ci,i,k} x[b,ci, d+i-2, h+i-2, w+k-2] * W[co,ci,i,0,k] + bias[co]
// x: (2,32,48,64,128) f32, W: (32,32,5,1,5), out: (2,32,48,68,128) f32.
//
// Quad-diagonal blocks: one block computes outputs (d0+q, h0+q), q=0..3,
// sharing 8 staged diagonal planes (d0-2+j, h0-2+j), j=0..7.
// R6: software-pipelined A-fragments (ping-pong prefetch across kk),
// kk-major weight packing, static-unrolled staging, setprio around MFMA.

#define NB   2
#define CIN  32
#define COUT 32
#define DD   48
#define HH   64
#define WW   128
#define DOUT 48
#define HO   68
#define WO   128

#define RS   256            // ushorts per col = 32 16B-chunks (8 planes * 4 octs)
#define NCOL 132            // col = w + 2; cols 0,1,130,131 always zero

typedef __attribute__((ext_vector_type(8))) short bf16x8;
typedef __attribute__((ext_vector_type(4))) float f32x4;

__device__ __forceinline__ unsigned short f32_to_bf16(float v) {
    unsigned int u; __builtin_memcpy(&u, &v, 4);
    u += 0x7FFFu + ((u >> 16) & 1u);        // RNE
    return (unsigned short)(u >> 16);
}
// packed pair conversion -> v_cvt_pk_bf16_f32 (1 instr for 2 floats)
__device__ __forceinline__ unsigned int pk2(float a, float b) {
    float2 t; t.x = a; t.y = b;
    __hip_bfloat162 r = __float22bfloat162_rn(t);
    unsigned int u; __builtin_memcpy(&u, &r, 4);
    return u;
}

// LDS: logical (col, chunk t), t = j*4 + oct (oct = ci>>3), j = plane 0..7.
// phys chunk = t ^ s, s = (col>>1)&7. col stride 512 B == 0 mod 128 B, so
// banks depend only on swizzled chunk; writes (cols 2*lane+{2,3}) and reads
// (cols wbase+lr+kk) both land at the 8-rounds-per-wave floor.
__device__ __forceinline__ int xs_chunk(int col, int t) {
    return col * RS + ((t ^ ((col >> 1) & 7)) << 3);
}

// Pre-pack weights into MFMA A-fragment order, kk-major for contiguity:
// frag f = (kk*5 + c)*2 + mt ; lane l ; 8 bf16 = W[mt*16+(l&15)][ci=(l>>4)*8+j][i=c][kk]
__global__ void prep_weights_kernel(const float* __restrict__ wgt,
                                    unsigned int* __restrict__ ws) {
    int s = blockIdx.x * 256 + threadIdx.x;     // 50 frags * 64 lanes = 3200 slots
    if (s >= 3200) return;
    int f = s >> 6, l = s & 63;
    int mt = f & 1, kkc = f >> 1;
    int kk = kkc / 5, c = kkc - kk * 5;         // kk-major
    int co = mt * 16 + (l & 15);
    int cib = (l >> 4) * 8;
    unsigned int u[4];
#pragma unroll
    for (int jp = 0; jp < 4; ++jp) {
        float v0 = wgt[co * 800 + (cib + 2 * jp + 0) * 25 + c * 5 + kk];
        float v1 = wgt[co * 800 + (cib + 2 * jp + 1) * 25 + c * 5 + kk];
        u[jp] = (unsigned int)f32_to_bf16(v0) | ((unsigned int)f32_to_bf16(v1) << 16);
    }
    uint4 pack; pack.x = u[0]; pack.y = u[1]; pack.z = u[2]; pack.w = u[3];
    reinterpret_cast<uint4*>(ws)[s] = pack;
}

__global__ void __launch_bounds__(512, 4)
dconv_kernel(const float* __restrict__ x,
             const float* __restrict__ bias,
             const bf16x8* __restrict__ wsf,   // packed A fragments
             float* __restrict__ out) {
    __shared__ __align__(16) unsigned short xs[NCOL * RS];   // 67584 B

    const int tid  = threadIdx.x;
    const int lane = tid & 63;
    const int wv   = tid >> 6;          // 0..7
    const int lr   = lane & 15;
    const int lg   = lane >> 4;

    // ---- quad-diagonal, XCD-chunked block remap ----
    int bid = blockIdx.x;
    int e   = (bid & 7) * 213 + (bid >> 3);
    int b   = (e >= 852) ? 1 : 0;
    int r0  = e - b * 852;
    int dlt = r0 / 12;
    int qq  = r0 - dlt * 12;
    const int d0 = 4 * qq;
    const int h0 = (d0 + dlt) % 71 - 3;     // -3..67

    // ---- early issue: kk=0 A-fragments + bias (latency hides under staging) ----
    const bf16x8* wl = wsf + lane;          // frag f at wl[f*64]
    bf16x8 acur[10];
#pragma unroll
    for (int t = 0; t < 10; ++t) acur[t] = wl[t * 64];
    float bs[8];
#pragma unroll
    for (int mt = 0; mt < 2; ++mt)
#pragma unroll
        for (int rg = 0; rg < 4; ++rg)
            bs[mt * 4 + rg] = bias[mt * 16 + lg * 4 + rg];

    // ---- zero the 4 always-zero halo cols (0,1,130,131), all 32 chunks ----
    if (tid < 128) {
        int colIdx = tid >> 5;              // 0..3
        int ch     = tid & 31;              // 0..31
        int col    = (colIdx < 2) ? colIdx : 128 + colIdx;
        f32x4 z = {};
        *reinterpret_cast<f32x4*>(&xs[col * RS + ch * 8]) = z;
    }

    // ---- stage 8 diagonal planes, transposed, chunk-granular b128 writes ----
    // group g = j*4 + oct = chunk index; lane owns w-pair (2*lane, 2*lane+1).
    {
        const int w0   = lane * 2;
        const int col0 = w0 + 2, col1 = w0 + 3;
        const size_t plane = (size_t)DD * HH * WW;
#pragma unroll 2
        for (int gi = 0; gi < 4; ++gi) {
            int g = gi * 8 + wv;                    // 0..31
            int j = g >> 2, oct = g & 3;
            int dz = d0 + j - 2, hz = h0 + j - 2;
            float2 v[8];
#pragma unroll
            for (int k = 0; k < 8; ++k) { v[k].x = 0.f; v[k].y = 0.f; }
            if (((unsigned)dz < (unsigned)DD) && ((unsigned)hz < (unsigned)HH)) {
                const float* base = x + ((((size_t)b * CIN + oct * 8) * DD + dz) * HH + hz) * WW + w0;
#pragma unroll
                for (int k = 0; k < 8; ++k)
                    v[k] = *reinterpret_cast<const float2*>(base + (size_t)k * plane);
            }
            uint4 c0, c1;
            c0.x = pk2(v[0].x, v[1].x); c0.y = pk2(v[2].x, v[3].x);
            c0.z = pk2(v[4].x, v[5].x); c0.w = pk2(v[6].x, v[7].x);
            c1.x = pk2(v[0].y, v[1].y); c1.y = pk2(v[2].y, v[3].y);
            c1.z = pk2(v[4].y, v[5].y); c1.w = pk2(v[6].y, v[7].y);
            *reinterpret_cast<uint4*>(&xs[xs_chunk(col0, g)]) = c0;
            *reinterpret_cast<uint4*>(&xs[xs_chunk(col1, g)]) = c1;
        }
    }
    __syncthreads();

    // ---- MFMA: wave wv owns w-tile [wv*16, wv*16+16), all 4 outputs ----
    // Fully unrolled kk with ping-pong A prefetch: kk+1's 10 frags issue
    // before kk's MFMA burst; counted vmcnt keeps them in flight.
    const int wbase = wv * 16;

    f32x4 acc[2][4] = {};   // [mt][q]

#pragma unroll
    for (int kk = 0; kk < 5; ++kk) {
        bf16x8 anext[10];
#pragma unroll
        for (int t = 0; t < 10; ++t)
            anext[t] = (kk < 4) ? wl[(kk + 1) * 640 + t * 64] : acur[t];

        // hoisted swizzle decomposition: phys chunk (j*4+lg)^s =
        //   (j>>1)*8 + ((j&1)^sb)*4 + (lg^(s&3)); reads become imm offsets.
        const int col = wbase + lr + kk;            // <= 112+15+4 = 131
        const int s   = (col >> 1) & 7;
        const int sb  = s >> 2;
        const int lg2 = lg ^ (s & 3);
        const unsigned short* pE = &xs[col * RS + ((sb * 4 + lg2) << 3)];
        const unsigned short* pO = &xs[col * RS + ((((sb ^ 1) << 2) + lg2) << 3)];

        __builtin_amdgcn_s_setprio(1);
#pragma unroll
        for (int j = 0; j < 8; ++j) {
            const unsigned short* p = (j & 1) ? pO : pE;
            bf16x8 bv = *reinterpret_cast<const bf16x8*>(p + (j >> 1) * 64);
            const int qlo = (j > 4) ? (j - 4) : 0;
            const int qhi = (j < 3) ? j : 3;
#pragma unroll
            for (int q = qlo; q <= qhi; ++q) {
                const int c = j - q;                // tap for output q at plane j
                acc[0][q] = __builtin_amdgcn_mfma_f32_16x16x32_bf16(acur[c * 2 + 0], bv, acc[0][q], 0, 0, 0);
                acc[1][q] = __builtin_amdgcn_mfma_f32_16x16x32_bf16(acur[c * 2 + 1], bv, acc[1][q], 0, 0, 0);
            }
        }
        __builtin_amdgcn_s_setprio(0);

#pragma unroll
        for (int t = 0; t < 10; ++t) acur[t] = anext[t];   // SSA rename, no moves
    }

    // ---- epilogue: D col=lane&15 (w), row=(lane>>4)*4+reg (co) ----
    const int w = wbase + lr;
#pragma unroll
    for (int q = 0; q < 4; ++q) {
        const int hq = h0 + q;
        if (hq < 0 || hq >= HO) continue;
        const int dq = d0 + q;
#pragma unroll
        for (int mt = 0; mt < 2; ++mt) {
#pragma unroll
            for (int rg = 0; rg < 4; ++rg) {
                int co = mt * 16 + lg * 4 + rg;
                out[((((size_t)b * COUT + co) * DOUT + dq) * HO + hq) * WO + w] =
                    acc[mt][q][rg] + bs[mt * 4 + rg];
            }
        }
    }
}

extern "C" void kernel_launch(void* const* d_in, const int* in_sizes, int n_in,
                              void* d_out, int out_size, void* d_ws, size_t ws_size,
                              hipStream_t stream) {
    const float* x    = (const float*)d_in[0];
    const float* wgt  = (const float*)d_in[1];
    const float* bias = (const float*)d_in[2];
    float* out = (float*)d_out;
    unsigned int* ws = (unsigned int*)d_ws;

    // pack weights into A-fragment layout (51200 B in d_ws)
    prep_weights_kernel<<<13, 256, 0, stream>>>(wgt, ws);

    dconv_kernel<<<1704, 512, 0, stream>>>(x, bias, (const bf16x8*)ws, out);
}

// Round 7
// 62.936 us; speedup vs baseline: 1.2738x; 1.2738x over previous
//
#include <hip/hip_runtime.h>
#include <hip/hip_bf16.h>

// DirectionalConv mode='down': out[b,co,d,h,w] =
//   sum_{ci,i,k} x[b,ci, d+i-2, h+i-2, w+k-2] * W[co,ci,i,0,k] + bias[co]
// x: (2,32,48,64,128) f32, W: (32,32,5,1,5), out: (2,32,48,68,128) f32.
//
// Quad-diagonal blocks: outputs (d0+q, h0+q), q=0..3, share 8 staged planes.
// R7: mt-split waves (wave = one co-half x 32-wide w-tile) -> 5 A-frags/kk,
// full-kk ping-pong prefetch fits in <=128 VGPR (R6 spilled at 20 frags).

#define NB   2
#define CIN  32
#define COUT 32
#define DD   48
#define HH   64
#define WW   128
#define DOUT 48
#define HO   68
#define WO   128

#define RS   256            // ushorts per col = 32 16B-chunks (8 planes * 4 octs)
#define NCOL 132            // col = w + 2; cols 0,1,130,131 always zero

typedef __attribute__((ext_vector_type(8))) short bf16x8;
typedef __attribute__((ext_vector_type(4))) float f32x4;

__device__ __forceinline__ unsigned short f32_to_bf16(float v) {
    unsigned int u; __builtin_memcpy(&u, &v, 4);
    u += 0x7FFFu + ((u >> 16) & 1u);        // RNE
    return (unsigned short)(u >> 16);
}
// packed pair conversion -> v_cvt_pk_bf16_f32 (1 instr for 2 floats)
__device__ __forceinline__ unsigned int pk2(float a, float b) {
    float2 t; t.x = a; t.y = b;
    __hip_bfloat162 r = __float22bfloat162_rn(t);
    unsigned int u; __builtin_memcpy(&u, &r, 4);
    return u;
}

// LDS: logical (col, chunk t), t = j*4 + oct (oct = ci>>3), j = plane 0..7.
// phys chunk = t ^ s, s = (col>>1)&7. col stride 512 B == 0 mod 128 B, so
// banks depend only on swizzled chunk; writes (cols 2*lane+{2,3}) and reads
// (cols wbase+nt*16+lr+kk) both land at the 8-rounds-per-wave floor.
__device__ __forceinline__ int xs_chunk(int col, int t) {
    return col * RS + ((t ^ ((col >> 1) & 7)) << 3);
}

// Pre-pack weights into MFMA A-fragment order, kk-major:
// frag f = (kk*5 + c)*2 + mt ; lane l ; 8 bf16 = W[mt*16+(l&15)][ci=(l>>4)*8+j][i=c][kk]
__global__ void prep_weights_kernel(const float* __restrict__ wgt,
                                    unsigned int* __restrict__ ws) {
    int s = blockIdx.x * 256 + threadIdx.x;     // 50 frags * 64 lanes = 3200 slots
    if (s >= 3200) return;
    int f = s >> 6, l = s & 63;
    int mt = f & 1, kkc = f >> 1;
    int kk = kkc / 5, c = kkc - kk * 5;         // kk-major
    int co = mt * 16 + (l & 15);
    int cib = (l >> 4) * 8;
    unsigned int u[4];
#pragma unroll
    for (int jp = 0; jp < 4; ++jp) {
        float v0 = wgt[co * 800 + (cib + 2 * jp + 0) * 25 + c * 5 + kk];
        float v1 = wgt[co * 800 + (cib + 2 * jp + 1) * 25 + c * 5 + kk];
        u[jp] = (unsigned int)f32_to_bf16(v0) | ((unsigned int)f32_to_bf16(v1) << 16);
    }
    uint4 pack; pack.x = u[0]; pack.y = u[1]; pack.z = u[2]; pack.w = u[3];
    reinterpret_cast<uint4*>(ws)[s] = pack;
}

__global__ void __launch_bounds__(512, 4)
dconv_kernel(const float* __restrict__ x,
             const float* __restrict__ bias,
             const bf16x8* __restrict__ wsf,   // packed A fragments
             float* __restrict__ out) {
    __shared__ __align__(16) unsigned short xs[NCOL * RS];   // 67584 B

    const int tid  = threadIdx.x;
    const int lane = tid & 63;
    const int wv   = tid >> 6;          // 0..7
    const int lr   = lane & 15;
    const int lg   = lane >> 4;
    const int mt   = wv & 1;            // co-half owned by this wave
    const int wbase = (wv >> 1) * 32;   // 32-wide w-tile

    // ---- quad-diagonal, XCD-chunked block remap ----
    int bid = blockIdx.x;
    int e   = (bid & 7) * 213 + (bid >> 3);
    int b   = (e >= 852) ? 1 : 0;
    int r0  = e - b * 852;
    int dlt = r0 / 12;
    int qq  = r0 - dlt * 12;
    const int d0 = 4 * qq;
    const int h0 = (d0 + dlt) % 71 - 3;     // -3..67

    // ---- early issue: kk=0 A-fragments + bias (hide under staging) ----
    const bf16x8* wl = wsf + lane;          // frag f at wl[f*64]
    bf16x8 aA[5], aB[5];
#pragma unroll
    for (int c = 0; c < 5; ++c) aA[c] = wl[(c * 2 + mt) * 64];
    float bs[4];
#pragma unroll
    for (int rg = 0; rg < 4; ++rg) bs[rg] = bias[mt * 16 + lg * 4 + rg];

    // ---- zero the 4 always-zero halo cols (0,1,130,131), all 32 chunks ----
    if (tid < 128) {
        int colIdx = tid >> 5;              // 0..3
        int ch     = tid & 31;              // 0..31
        int col    = (colIdx < 2) ? colIdx : 128 + colIdx;
        f32x4 z = {};
        *reinterpret_cast<f32x4*>(&xs[col * RS + ch * 8]) = z;
    }

    // ---- stage 8 diagonal planes, transposed, chunk-granular b128 writes ----
    {
        const int w0   = lane * 2;
        const int col0 = w0 + 2, col1 = w0 + 3;
        const size_t plane = (size_t)DD * HH * WW;
#pragma unroll 2
        for (int gi = 0; gi < 4; ++gi) {
            int g = gi * 8 + wv;                    // 0..31
            int j = g >> 2, oct = g & 3;
            int dz = d0 + j - 2, hz = h0 + j - 2;
            float2 v[8];
#pragma unroll
            for (int k = 0; k < 8; ++k) { v[k].x = 0.f; v[k].y = 0.f; }
            if (((unsigned)dz < (unsigned)DD) && ((unsigned)hz < (unsigned)HH)) {
                const float* base = x + ((((size_t)b * CIN + oct * 8) * DD + dz) * HH + hz) * WW + w0;
#pragma unroll
                for (int k = 0; k < 8; ++k)
                    v[k] = *reinterpret_cast<const float2*>(base + (size_t)k * plane);
            }
            uint4 c0, c1;
            c0.x = pk2(v[0].x, v[1].x); c0.y = pk2(v[2].x, v[3].x);
            c0.z = pk2(v[4].x, v[5].x); c0.w = pk2(v[6].x, v[7].x);
            c1.x = pk2(v[0].y, v[1].y); c1.y = pk2(v[2].y, v[3].y);
            c1.z = pk2(v[4].y, v[5].y); c1.w = pk2(v[6].y, v[7].y);
            *reinterpret_cast<uint4*>(&xs[xs_chunk(col0, g)]) = c0;
            *reinterpret_cast<uint4*>(&xs[xs_chunk(col1, g)]) = c1;
        }
    }
    __syncthreads();

    // ---- MFMA: wave = (mt, 32w, 4q); full-kk ping-pong A prefetch ----
    f32x4 acc[4][2] = {};   // [q][nt]

    // prefetch kk+1's 5 frags into DST (static names, no runtime select)
#define PREFA(DST, KK1)                                                        \
    _Pragma("unroll") for (int c = 0; c < 5; ++c)                              \
        DST[c] = wl[(((KK1) * 5 + c) * 2 + mt) * 64];

    // one kk step: 2 nt x { 8 ds_read_b128 + up-to-8 MFMA each }
#define STEPK(KK, ACU)                                                         \
    {                                                                          \
        __builtin_amdgcn_s_setprio(1);                                         \
        _Pragma("unroll") for (int nt = 0; nt < 2; ++nt) {                     \
            const int col = wbase + nt * 16 + lr + (KK);                       \
            const int s   = (col >> 1) & 7;                                    \
            const int sb  = s >> 2;                                            \
            const int lg2 = lg ^ (s & 3);                                      \
            const unsigned short* pE = &xs[col * RS + ((sb * 4 + lg2) << 3)];  \
            const unsigned short* pO = &xs[col * RS + ((((sb ^ 1) << 2) + lg2) << 3)]; \
            _Pragma("unroll") for (int j = 0; j < 8; ++j) {                    \
                const unsigned short* p = (j & 1) ? pO : pE;                   \
                bf16x8 bv = *reinterpret_cast<const bf16x8*>(p + (j >> 1) * 64); \
                const int qlo = (j > 4) ? (j - 4) : 0;                         \
                const int qhi = (j < 3) ? j : 3;                               \
                _Pragma("unroll") for (int q = qlo; q <= qhi; ++q) {           \
                    acc[q][nt] = __builtin_amdgcn_mfma_f32_16x16x32_bf16(      \
                        ACU[j - q], bv, acc[q][nt], 0, 0, 0);                  \
                }                                                              \
            }                                                                  \
        }                                                                      \
        __builtin_amdgcn_s_setprio(0);                                         \
    }

    PREFA(aB, 1) STEPK(0, aA)
    PREFA(aA, 2) STEPK(1, aB)
    PREFA(aB, 3) STEPK(2, aA)
    PREFA(aA, 4) STEPK(3, aB)
    STEPK(4, aA)
#undef PREFA
#undef STEPK

    // ---- epilogue: D col=lane&15 (w), row=(lane>>4)*4+reg (co) ----
#pragma unroll
    for (int q = 0; q < 4; ++q) {
        const int hq = h0 + q;
        if (hq < 0 || hq >= HO) continue;
        const int dq = d0 + q;
#pragma unroll
        for (int nt = 0; nt < 2; ++nt) {
            const int w = wbase + nt * 16 + lr;
#pragma unroll
            for (int rg = 0; rg < 4; ++rg) {
                int co = mt * 16 + lg * 4 + rg;
                out[((((size_t)b * COUT + co) * DOUT + dq) * HO + hq) * WO + w] =
                    acc[q][nt][rg] + bs[rg];
            }
        }
    }
}

extern "C" void kernel_launch(void* const* d_in, const int* in_sizes, int n_in,
                              void* d_out, int out_size, void* d_ws, size_t ws_size,
                              hipStream_t stream) {
    const float* x    = (const float*)d_in[0];
    const float* wgt  = (const float*)d_in[1];
    const float* bias = (const float*)d_in[2];
    float* out = (float*)d_out;
    unsigned int* ws = (unsigned int*)d_ws;

    // pack weights into A-fragment layout (51200 B in d_ws)
    prep_weights_kernel<<<13, 256, 0, stream>>>(wgt, ws);

    dconv_kernel<<<1704, 512, 0, stream>>>(x, bias, (const bf16x8*)ws, out);
}

// Round 8
// 62.047 us; speedup vs baseline: 1.2921x; 1.0143x over previous
//
#include <hip/hip_runtime.h>
#include <hip/hip_bf16.h>

// DirectionalConv mode='down': out[b,co,d,h,w] =
//   sum_{ci,i,k} x[b,ci, d+i-2, h+i-2, w+k-2] * W[co,ci,i,0,k] + bias[co]
// x: (2,32,48,64,128) f32, W: (32,32,5,1,5), out: (2,32,48,68,128) f32.
//
// Quad-diagonal blocks: outputs (d0+q, h0+q), q=0..3, share 8 staged planes.
// R8: conflict-free LDS swizzle s = col&7 (8 consecutive lanes -> 8 distinct
// bank-quads on BOTH read and write), enabled by col-per-lane staging
// (each lane owns one col, writes one b128 chunk per plane).

#define NB   2
#define CIN  32
#define COUT 32
#define DD   48
#define HH   64
#define WW   128
#define DOUT 48
#define HO   68
#define WO   128

#define RS   256            // ushorts per col = 32 16B-chunks (8 planes * 4 octs)
#define NCOL 132            // col = w + 2; cols 0,1,130,131 always zero

typedef __attribute__((ext_vector_type(8))) short bf16x8;
typedef __attribute__((ext_vector_type(4))) float f32x4;

__device__ __forceinline__ unsigned short f32_to_bf16(float v) {
    unsigned int u; __builtin_memcpy(&u, &v, 4);
    u += 0x7FFFu + ((u >> 16) & 1u);        // RNE
    return (unsigned short)(u >> 16);
}
// packed pair conversion -> v_cvt_pk_bf16_f32 (1 instr for 2 floats)
__device__ __forceinline__ unsigned int pk2(float a, float b) {
    float2 t; t.x = a; t.y = b;
    __hip_bfloat162 r = __float22bfloat162_rn(t);
    unsigned int u; __builtin_memcpy(&u, &r, 4);
    return u;
}

// LDS: logical (col, chunk t), t = j*4 + oct (oct = ci>>3), j = plane 0..7.
// phys chunk P = t ^ s, s = col & 7 (XOR on low 3 bits; j's bit kept in t>>3).
// col stride 512 B == 0 mod 128 B -> bank-quad = P & 7.
//  write: lane owns col = wh*64+lane+2 -> 8 consecutive lanes: 8 distinct s
//  read : col = C+lr (lr=lane&15)     -> 8 consecutive lanes: 8 distinct s
// both at the 8-cycle b128 floor, zero excess conflicts.

// Pre-pack weights into MFMA A-fragment order, kk-major:
// frag f = (kk*5 + c)*2 + mt ; lane l ; 8 bf16 = W[mt*16+(l&15)][ci=(l>>4)*8+j][i=c][kk]
__global__ void prep_weights_kernel(const float* __restrict__ wgt,
                                    unsigned int* __restrict__ ws) {
    int s = blockIdx.x * 256 + threadIdx.x;     // 50 frags * 64 lanes = 3200 slots
    if (s >= 3200) return;
    int f = s >> 6, l = s & 63;
    int mt = f & 1, kkc = f >> 1;
    int kk = kkc / 5, c = kkc - kk * 5;         // kk-major
    int co = mt * 16 + (l & 15);
    int cib = (l >> 4) * 8;
    unsigned int u[4];
#pragma unroll
    for (int jp = 0; jp < 4; ++jp) {
        float v0 = wgt[co * 800 + (cib + 2 * jp + 0) * 25 + c * 5 + kk];
        float v1 = wgt[co * 800 + (cib + 2 * jp + 1) * 25 + c * 5 + kk];
        u[jp] = (unsigned int)f32_to_bf16(v0) | ((unsigned int)f32_to_bf16(v1) << 16);
    }
    uint4 pack; pack.x = u[0]; pack.y = u[1]; pack.z = u[2]; pack.w = u[3];
    reinterpret_cast<uint4*>(ws)[s] = pack;
}

__global__ void __launch_bounds__(512, 4)
dconv_kernel(const float* __restrict__ x,
             const float* __restrict__ bias,
             const bf16x8* __restrict__ wsf,   // packed A fragments
             float* __restrict__ out) {
    __shared__ __align__(16) unsigned short xs[NCOL * RS];   // 67584 B

    const int tid  = threadIdx.x;
    const int lane = tid & 63;
    const int wv   = tid >> 6;          // 0..7
    const int lr   = lane & 15;
    const int lg   = lane >> 4;
    const int mt   = wv & 1;            // co-half owned by this wave (MFMA phase)
    const int wbase = (wv >> 1) * 32;   // 32-wide w-tile (MFMA phase)

    // ---- quad-diagonal, XCD-chunked block remap ----
    int bid = blockIdx.x;
    int e   = (bid & 7) * 213 + (bid >> 3);
    int b   = (e >= 852) ? 1 : 0;
    int r0  = e - b * 852;
    int dlt = r0 / 12;
    int qq  = r0 - dlt * 12;
    const int d0 = 4 * qq;
    const int h0 = (d0 + dlt) % 71 - 3;     // -3..67

    // ---- early issue: kk=0 A-fragments + bias (hide under staging) ----
    const bf16x8* wl = wsf + lane;          // frag f at wl[f*64]
    bf16x8 aA[5], aB[5];
#pragma unroll
    for (int c = 0; c < 5; ++c) aA[c] = wl[(c * 2 + mt) * 64];
    float bs[4];
#pragma unroll
    for (int rg = 0; rg < 4; ++rg) bs[rg] = bias[mt * 16 + lg * 4 + rg];

    // ---- zero the 4 always-zero halo cols (0,1,130,131), all 32 chunks ----
    if (tid < 128) {
        int colIdx = tid >> 5;              // 0..3
        int ch     = tid & 31;              // 0..31
        int col    = (colIdx < 2) ? colIdx : 128 + colIdx;
        f32x4 z = {};
        *reinterpret_cast<f32x4*>(&xs[col * RS + ch * 8]) = z;
    }

    // ---- stage 8 diagonal planes: col-per-lane, one b128 chunk per plane ----
    // wave role: oct = wv>>1 (ci octet), wh = wv&1 (w half); lane owns one col.
    {
        const int oct = wv >> 1, wh = wv & 1;
        const int w0  = wh * 64 + lane;     // 0..127
        const int col = w0 + 2;
        const int s   = col & 7;
        unsigned short* cbase = &xs[col * RS];
        const size_t plane = (size_t)DD * HH * WW;
        const float* xoct = x + ((size_t)b * CIN + oct * 8) * plane + w0;
#pragma unroll 4
        for (int j = 0; j < 8; ++j) {
            int dz = d0 + j - 2, hz = h0 + j - 2;
            float v[8];
#pragma unroll
            for (int k = 0; k < 8; ++k) v[k] = 0.f;
            if (((unsigned)dz < (unsigned)DD) && ((unsigned)hz < (unsigned)HH)) {
                const float* p = xoct + ((size_t)dz * HH + hz) * WW;
#pragma unroll
                for (int k = 0; k < 8; ++k) v[k] = p[(size_t)k * plane];
            }
            uint4 ch;
            ch.x = pk2(v[0], v[1]); ch.y = pk2(v[2], v[3]);
            ch.z = pk2(v[4], v[5]); ch.w = pk2(v[6], v[7]);
            int P = (j * 4 + oct) ^ s;
            *reinterpret_cast<uint4*>(cbase + P * 8) = ch;
        }
    }
    __syncthreads();

    // ---- MFMA: wave = (mt, 32w, 4q); full-kk ping-pong A prefetch ----
    f32x4 acc[4][2] = {};   // [q][nt]

#define PREFA(DST, KK1)                                                        \
    _Pragma("unroll") for (int c = 0; c < 5; ++c)                              \
        DST[c] = wl[(((KK1) * 5 + c) * 2 + mt) * 64];

    // phys chunk for (j, lg) at col: P = (j ^ sb)*4 + (lg ^ (s&3)), sb = s>>2.
    // two-pointer form: even j -> pE + j*32, odd j -> pO + j*32 (ushorts).
#define STEPK(KK, ACU)                                                         \
    {                                                                          \
        __builtin_amdgcn_s_setprio(1);                                         \
        _Pragma("unroll") for (int nt = 0; nt < 2; ++nt) {                     \
            const int col = wbase + nt * 16 + lr + (KK);                       \
            const int s   = col & 7;                                           \
            const int sb  = s >> 2;                                            \
            const int lg2 = lg ^ (s & 3);                                      \
            const unsigned short* pc = &xs[col * RS + lg2 * 8];                \
            const unsigned short* pE = pc + sb * 32;                           \
            const unsigned short* pO = pc - sb * 32;                           \
            _Pragma("unroll") for (int j = 0; j < 8; ++j) {                    \
                const unsigned short* p = (j & 1) ? pO : pE;                   \
                bf16x8 bv = *reinterpret_cast<const bf16x8*>(p + j * 32);      \
                const int qlo = (j > 4) ? (j - 4) : 0;                         \
                const int qhi = (j < 3) ? j : 3;                               \
                _Pragma("unroll") for (int q = qlo; q <= qhi; ++q) {           \
                    acc[q][nt] = __builtin_amdgcn_mfma_f32_16x16x32_bf16(      \
                        ACU[j - q], bv, acc[q][nt], 0, 0, 0);                  \
                }                                                              \
            }                                                                  \
        }                                                                      \
        __builtin_amdgcn_s_setprio(0);                                         \
    }

    PREFA(aB, 1) STEPK(0, aA)
    PREFA(aA, 2) STEPK(1, aB)
    PREFA(aB, 3) STEPK(2, aA)
    PREFA(aA, 4) STEPK(3, aB)
    STEPK(4, aA)
#undef PREFA
#undef STEPK

    // ---- epilogue: D col=lane&15 (w), row=(lane>>4)*4+reg (co) ----
#pragma unroll
    for (int q = 0; q < 4; ++q) {
        const int hq = h0 + q;
        if (hq < 0 || hq >= HO) continue;
        const int dq = d0 + q;
#pragma unroll
        for (int nt = 0; nt < 2; ++nt) {
            const int w = wbase + nt * 16 + lr;
#pragma unroll
            for (int rg = 0; rg < 4; ++rg) {
                int co = mt * 16 + lg * 4 + rg;
                out[((((size_t)b * COUT + co) * DOUT + dq) * HO + hq) * WO + w] =
                    acc[q][nt][rg] + bs[rg];
            }
        }
    }
}

extern "C" void kernel_launch(void* const* d_in, const int* in_sizes, int n_in,
                              void* d_out, int out_size, void* d_ws, size_t ws_size,
                              hipStream_t stream) {
    const float* x    = (const float*)d_in[0];
    const float* wgt  = (const float*)d_in[1];
    const float* bias = (const float*)d_in[2];
    float* out = (float*)d_out;
    unsigned int* ws = (unsigned int*)d_ws;

    // pack weights into A-fragment layout (51200 B in d_ws)
    prep_weights_kernel<<<13, 256, 0, stream>>>(wgt, ws);

    dconv_kernel<<<1704, 512, 0, stream>>>(x, bias, (const bf16x8*)ws, out);
}